// Round 1
// baseline (667.175 us; speedup 1.0000x reference)
//
#include <hip/hip_runtime.h>
#include <hip/hip_bf16.h>
#include <math.h>

#define N_ROWS 8192
#define DIM    1024

typedef __bf16 bf16_t;
typedef __bf16 bf16x4 __attribute__((ext_vector_type(4)));
typedef __bf16 bf16x8 __attribute__((ext_vector_type(8)));
typedef float  f32x4  __attribute__((ext_vector_type(4)));

// Order-preserving float -> uint map (for atomicMax on floats incl. negatives)
__device__ __forceinline__ unsigned fmap(float f) {
    unsigned u = __float_as_uint(f);
    return (u & 0x80000000u) ? ~u : (u | 0x80000000u);
}
__device__ __forceinline__ float funmap(unsigned u) {
    return (u & 0x80000000u) ? __uint_as_float(u ^ 0x80000000u)
                             : __uint_as_float(~u);
}

// ---------------------------------------------------------------------------
// Kernel 1: L2-normalize each row (fp32 in), write bf16 normalized matrix,
// and init row_max[] to 0 (mapped value 0 < any real float's mapping).
// ---------------------------------------------------------------------------
__global__ __launch_bounds__(256) void k_normalize(const float* __restrict__ x,
                                                   bf16_t* __restrict__ xb,
                                                   unsigned* __restrict__ row_max) {
    const int row = blockIdx.x;
    const int tid = threadIdx.x;
    const float4* xr = reinterpret_cast<const float4*>(x + (size_t)row * DIM);
    float4 v = xr[tid];                       // 256 threads * 4 floats = 1024
    float ss = v.x * v.x + v.y * v.y + v.z * v.z + v.w * v.w;
    #pragma unroll
    for (int m = 32; m >= 1; m >>= 1) ss += __shfl_xor(ss, m);
    __shared__ float wss[4];
    const int wid = tid >> 6;
    if ((tid & 63) == 0) wss[wid] = ss;
    __syncthreads();
    const float tot = wss[0] + wss[1] + wss[2] + wss[3];
    const float scale = 1.0f / fmaxf(sqrtf(tot), 1e-12f);

    bf16x4 o;
    o[0] = (bf16_t)(v.x * scale);
    o[1] = (bf16_t)(v.y * scale);
    o[2] = (bf16_t)(v.z * scale);
    o[3] = (bf16_t)(v.w * scale);
    reinterpret_cast<bf16x4*>(xb + (size_t)row * DIM)[tid] = o;

    if (tid == 0) row_max[row] = 0u;          // mapped -inf surrogate
}

// ---------------------------------------------------------------------------
// Kernel 2: row-max of sim = Xb * Xb^T, diagonal masked, clamped to <= 1.
// 128x128 tile per block; 4 waves, each wave owns 32 rows x 128 cols.
// mfma_f32_16x16x32_bf16; A/B fragments load identically from Xb:
//   frag[lane] = Xb[tileBase + (l&15)][k + (l>>4)*8 + 0..7]   (16B/lane)
// C/D layout (verified, guide S3): col = lane&15, row = (lane>>4)*4 + reg.
// ---------------------------------------------------------------------------
__global__ __launch_bounds__(256) void k_simmax(const bf16_t* __restrict__ xb,
                                                unsigned* __restrict__ row_max) {
    const int w  = threadIdx.x >> 6;
    const int l  = threadIdx.x & 63;
    const int lr = l & 15;                    // row-in-subtile for A/B frags
    const int lk = (l >> 4) * 8;              // k offset within 32-chunk
    const int i0 = blockIdx.y * 128 + w * 32; // this wave's first output row
    const int j0 = blockIdx.x * 128;          // block's first output col

    f32x4 acc[2][8] = {};

    const bf16_t* aB0 = xb + (size_t)(i0 + lr) * DIM + lk;
    const bf16_t* aB1 = xb + (size_t)(i0 + 16 + lr) * DIM + lk;
    const bf16_t* bB  = xb + (size_t)(j0 + lr) * DIM + lk;

    for (int k = 0; k < DIM; k += 32) {
        bf16x8 a0 = *reinterpret_cast<const bf16x8*>(aB0 + k);
        bf16x8 a1 = *reinterpret_cast<const bf16x8*>(aB1 + k);
        #pragma unroll
        for (int n = 0; n < 8; ++n) {
            bf16x8 b = *reinterpret_cast<const bf16x8*>(bB + (size_t)n * 16 * DIM + k);
            acc[0][n] = __builtin_amdgcn_mfma_f32_16x16x32_bf16(a0, b, acc[0][n], 0, 0, 0);
            acc[1][n] = __builtin_amdgcn_mfma_f32_16x16x32_bf16(a1, b, acc[1][n], 0, 0, 0);
        }
    }

    // Epilogue: clamp, mask diagonal, row-max reduce, one atomic per row.
    #pragma unroll
    for (int m = 0; m < 2; ++m) {
        float rm[4] = {-3.0e38f, -3.0e38f, -3.0e38f, -3.0e38f};
        #pragma unroll
        for (int n = 0; n < 8; ++n) {
            const int col = j0 + n * 16 + lr;
            #pragma unroll
            for (int j = 0; j < 4; ++j) {
                const int row = i0 + m * 16 + (l >> 4) * 4 + j;
                float s = fminf(acc[m][n][j], 1.0f);
                if (row == col) s = -3.0e38f;  // mask self-similarity
                rm[j] = fmaxf(rm[j], s);
            }
        }
        #pragma unroll
        for (int j = 0; j < 4; ++j) {
            #pragma unroll
            for (int mask = 1; mask < 16; mask <<= 1)
                rm[j] = fmaxf(rm[j], __shfl_xor(rm[j], mask));
            if ((l & 15) == 0)
                atomicMax(&row_max[i0 + m * 16 + (l >> 4) * 4 + j], fmap(rm[j]));
        }
    }
}

// ---------------------------------------------------------------------------
// Kernel 3: loss = -mean(log(sqrt(2 - 2*min(max_sim,1) + 1e-4) + 1e-8))
// ---------------------------------------------------------------------------
__global__ __launch_bounds__(256) void k_finish(const unsigned* __restrict__ row_max,
                                                float* __restrict__ out) {
    const int tid = threadIdx.x;
    float sum = 0.0f;
    for (int i = tid; i < N_ROWS; i += 256) {
        float sim = fminf(funmap(row_max[i]), 1.0f);
        float dist = sqrtf(2.0f - 2.0f * sim + 1e-4f);
        sum += logf(dist + 1e-8f);
    }
    #pragma unroll
    for (int m = 32; m >= 1; m >>= 1) sum += __shfl_xor(sum, m);
    __shared__ float wss[4];
    const int wid = tid >> 6;
    if ((tid & 63) == 0) wss[wid] = sum;
    __syncthreads();
    if (tid == 0) out[0] = -(wss[0] + wss[1] + wss[2] + wss[3]) / (float)N_ROWS;
}

// ---------------------------------------------------------------------------
extern "C" void kernel_launch(void* const* d_in, const int* in_sizes, int n_in,
                              void* d_out, int out_size, void* d_ws, size_t ws_size,
                              hipStream_t stream) {
    const float* x = (const float*)d_in[0];
    bf16_t* xb = (bf16_t*)d_ws;                                   // 16 MiB
    unsigned* row_max = (unsigned*)((char*)d_ws +
                         (size_t)N_ROWS * DIM * sizeof(bf16_t));  // +32 KiB
    float* out = (float*)d_out;

    k_normalize<<<N_ROWS, 256, 0, stream>>>(x, xb, row_max);
    dim3 grid(N_ROWS / 128, N_ROWS / 128);
    k_simmax<<<grid, 256, 0, stream>>>(xb, row_max);
    k_finish<<<1, 256, 0, stream>>>(row_max, out);
}

// Round 4
// 186.443 us; speedup vs baseline: 3.5784x; 3.5784x over previous
//
#include <hip/hip_runtime.h>
#include <hip/hip_bf16.h>
#include <math.h>

#define N_ROWS 8192
#define DIM    1024
#define NB     (N_ROWS / 128)   // 64 tiles per side
#define NT     (NB * (NB + 1) / 2)  // 2080 triangular blocks

typedef __bf16 bf16_t;
typedef __bf16 bf16x4 __attribute__((ext_vector_type(4)));
typedef __bf16 bf16x8 __attribute__((ext_vector_type(8)));
typedef float  f32x4  __attribute__((ext_vector_type(4)));

// global -> LDS direct copy, 16B per lane; LDS dest must be wave-uniform
#define GLOAD_LDS(g, s) __builtin_amdgcn_global_load_lds(                      \
    (const __attribute__((address_space(1))) void*)(g),                        \
    (__attribute__((address_space(3))) void*)(s), 16, 0, 0)

// Order-preserving float -> uint map (atomicMax on floats incl. negatives)
__device__ __forceinline__ unsigned fmap(float f) {
    unsigned u = __float_as_uint(f);
    return (u & 0x80000000u) ? ~u : (u | 0x80000000u);
}
__device__ __forceinline__ float funmap(unsigned u) {
    return (u & 0x80000000u) ? __uint_as_float(u ^ 0x80000000u)
                             : __uint_as_float(~u);
}

// ---------------------------------------------------------------------------
// Kernel 1: L2-normalize each row (fp32 in), write bf16 matrix, init row_max.
// ---------------------------------------------------------------------------
__global__ __launch_bounds__(256) void k_normalize(const float* __restrict__ x,
                                                   bf16_t* __restrict__ xb,
                                                   unsigned* __restrict__ row_max) {
    const int row = blockIdx.x;
    const int tid = threadIdx.x;
    const float4* xr = reinterpret_cast<const float4*>(x + (size_t)row * DIM);
    float4 v = xr[tid];
    float ss = v.x * v.x + v.y * v.y + v.z * v.z + v.w * v.w;
    #pragma unroll
    for (int m = 32; m >= 1; m >>= 1) ss += __shfl_xor(ss, m);
    __shared__ float wss[4];
    if ((tid & 63) == 0) wss[tid >> 6] = ss;
    __syncthreads();
    const float tot = wss[0] + wss[1] + wss[2] + wss[3];
    const float scale = 1.0f / fmaxf(sqrtf(tot), 1e-12f);

    bf16x4 o;
    o[0] = (bf16_t)(v.x * scale);
    o[1] = (bf16_t)(v.y * scale);
    o[2] = (bf16_t)(v.z * scale);
    o[3] = (bf16_t)(v.w * scale);
    reinterpret_cast<bf16x4*>(xb + (size_t)row * DIM)[tid] = o;

    if (tid == 0) row_max[row] = 0u;   // mapped surrogate for -inf
}

// ---------------------------------------------------------------------------
// Kernel 2: row/col-max of sim = Xb*Xb^T over upper-triangular 128x128 tiles.
// m97 structure: LDS-staged A/B tiles (global_load_lds w=16), 2x2 waves,
// 64x64 output per wave, BK=32, 8 ds_read_b128 + 16 MFMA per K-step.
// C/D layout: col = lane&15, row = (lane>>4)*4 + reg.
// ---------------------------------------------------------------------------
__global__ __launch_bounds__(256) void k_simmax(const bf16_t* __restrict__ xb,
                                                unsigned* __restrict__ row_max) {
    __shared__ bf16_t smA[128 * 32];
    __shared__ bf16_t smB[128 * 32];
    const int tid = threadIdx.x;
    const int w  = tid >> 6;
    const int l  = tid & 63;
    const int lr = l & 15;
    const int lk = (l >> 4) * 8;
    const int wr = w >> 1, wc = w & 1;

    // linear block id -> upper-triangular (bi, bj), bi <= bj
    int t = blockIdx.x;
    #define TOFF(b) ((b) * NB - ((b) * ((b) - 1)) / 2)
    int bi = (int)((float)(2 * NB + 1 -
                sqrtf((float)((2 * NB + 1) * (2 * NB + 1) - 8 * t))) * 0.5f);
    if (bi < 0) bi = 0;
    if (bi > NB - 1) bi = NB - 1;
    while (TOFF(bi + 1) <= t) ++bi;
    while (TOFF(bi) > t) --bi;
    const int bj = bi + (t - TOFF(bi));
    const int i0 = bi * 128, j0 = bj * 128;

    // staging: linear slot idx = q*256 + tid covers row = idx>>2, 8-elem
    // chunk = idx&3 of a row-major [128][32] bf16 tile (16B per lane).
    const bf16_t* gA = xb + (size_t)(i0 + (tid >> 2)) * DIM + (tid & 3) * 8;
    const bf16_t* gB = xb + (size_t)(j0 + (tid >> 2)) * DIM + (tid & 3) * 8;
    const int wbase = (tid & ~63) * 8;      // wave-uniform LDS elem offset

    f32x4 acc[4][4] = {};
    const bf16_t* pa = smA + (wr * 64 + lr) * 32 + lk;
    const bf16_t* pb = smB + (wc * 64 + lr) * 32 + lk;

    for (int k = 0; k < DIM; k += 32) {
        GLOAD_LDS(gA + k,            smA + wbase);
        GLOAD_LDS(gA + 64 * DIM + k, smA + 2048 + wbase);
        GLOAD_LDS(gB + k,            smB + wbase);
        GLOAD_LDS(gB + 64 * DIM + k, smB + 2048 + wbase);
        __syncthreads();

        bf16x8 af[4], bf[4];
        #pragma unroll
        for (int m = 0; m < 4; ++m) af[m] = *(const bf16x8*)(pa + m * 512);
        #pragma unroll
        for (int n = 0; n < 4; ++n) bf[n] = *(const bf16x8*)(pb + n * 512);
        #pragma unroll
        for (int m = 0; m < 4; ++m)
            #pragma unroll
            for (int n = 0; n < 4; ++n)
                acc[m][n] = __builtin_amdgcn_mfma_f32_16x16x32_bf16(
                                af[m], bf[n], acc[m][n], 0, 0, 0);
        __syncthreads();
    }

    // Epilogue. Row-maxes for this wave's 64 rows (reduce over lr group).
    #pragma unroll
    for (int m = 0; m < 4; ++m) {
        #pragma unroll
        for (int j = 0; j < 4; ++j) {
            const int rowg = i0 + wr * 64 + m * 16 + (l >> 4) * 4 + j;
            float rm = -3.0e38f;
            #pragma unroll
            for (int n = 0; n < 4; ++n) {
                float s = acc[m][n][j];
                if (rowg == (j0 + wc * 64 + n * 16 + lr)) s = -3.0e38f;
                rm = fmaxf(rm, s);
            }
            #pragma unroll
            for (int mask = 1; mask < 16; mask <<= 1)
                rm = fmaxf(rm, __shfl_xor(rm, mask));
            if (lr == 0)
                atomicMax(&row_max[rowg], fmap(fminf(rm, 1.0f)));
        }
    }
    // Col-maxes feed the symmetric rows (off-diagonal blocks only).
    if (bi != bj) {
        #pragma unroll
        for (int n = 0; n < 4; ++n) {
            const int colg = j0 + wc * 64 + n * 16 + lr;
            float cm = -3.0e38f;
            #pragma unroll
            for (int m = 0; m < 4; ++m)
                #pragma unroll
                for (int j = 0; j < 4; ++j)
                    cm = fmaxf(cm, acc[m][n][j]);
            cm = fmaxf(cm, __shfl_xor(cm, 16));
            cm = fmaxf(cm, __shfl_xor(cm, 32));
            if (l < 16)
                atomicMax(&row_max[colg], fmap(fminf(cm, 1.0f)));
        }
    }
}

// ---------------------------------------------------------------------------
// Kernel 3: loss = -mean(log(sqrt(2 - 2*min(max_sim,1) + 1e-4) + 1e-8))
// ---------------------------------------------------------------------------
__global__ __launch_bounds__(256) void k_finish(const unsigned* __restrict__ row_max,
                                                float* __restrict__ out) {
    const int tid = threadIdx.x;
    float sum = 0.0f;
    for (int i = tid; i < N_ROWS; i += 256) {
        float sim = fminf(funmap(row_max[i]), 1.0f);
        float dist = sqrtf(2.0f - 2.0f * sim + 1e-4f);
        sum += logf(dist + 1e-8f);
    }
    #pragma unroll
    for (int m = 32; m >= 1; m >>= 1) sum += __shfl_xor(sum, m);
    __shared__ float wss[4];
    if ((tid & 63) == 0) wss[tid >> 6] = sum;
    __syncthreads();
    if (tid == 0) out[0] = -(wss[0] + wss[1] + wss[2] + wss[3]) / (float)N_ROWS;
}

// ---------------------------------------------------------------------------
extern "C" void kernel_launch(void* const* d_in, const int* in_sizes, int n_in,
                              void* d_out, int out_size, void* d_ws, size_t ws_size,
                              hipStream_t stream) {
    const float* x = (const float*)d_in[0];
    bf16_t* xb = (bf16_t*)d_ws;                                   // 16 MiB
    unsigned* row_max = (unsigned*)((char*)d_ws +
                         (size_t)N_ROWS * DIM * sizeof(bf16_t));  // +32 KiB
    float* out = (float*)d_out;

    k_normalize<<<N_ROWS, 256, 0, stream>>>(x, xb, row_max);
    k_simmax<<<NT, 256, 0, stream>>>(xb, row_max);
    k_finish<<<1, 256, 0, stream>>>(row_max, out);
}